// Round 6
// baseline (561.689 us; speedup 1.0000x reference)
//
#include <hip/hip_runtime.h>

#define NKER  128
#define INDIM 1024
#define UNITS 1024

typedef __attribute__((ext_vector_type(8)))  short          bf16x8;
typedef __attribute__((ext_vector_type(4)))  float          f32x4;
typedef __attribute__((ext_vector_type(8)))  unsigned short u16x8;

// raw barrier discipline: s_barrier does NOT drain vmcnt; global loads stay
// in flight across barriers with compiler-counted vmcnt at their uses.
#define LGKM0   asm volatile("s_waitcnt lgkmcnt(0)" ::: "memory")
#define BAR()   __builtin_amdgcn_s_barrier()
#define SCHED0  __builtin_amdgcn_sched_barrier(0)

__device__ __forceinline__ unsigned short f2bf(float f) {
    return __builtin_bit_cast(unsigned short, static_cast<__bf16>(f));
}

// swizzled LDS element index for (row r, k in 0..31) — verified conflict-free
__device__ __forceinline__ int swzidx(int r, int k) {
    return r * 32 + ((((k >> 3) ^ ((r >> 1) & 3)) << 3) | (k & 7));
}

__global__ void __launch_bounds__(512, 2)
dense_local(const float* __restrict__ X, const float* __restrict__ Kn,
            float* __restrict__ Out)
{
    // B only: 2 x 128n x 32k bf16 = 16 KB total. A never touches LDS.
    __shared__ __align__(16) unsigned short lB[2][128 * 32];

    // XCD swizzle: 2048 wgs, 256/XCD, k-major inside an XCD chunk (bijective)
    const int bid  = blockIdx.x;
    const int wg   = (bid & 7) * 256 + (bid >> 3);
    const int kidx = wg >> 4;
    const int tile = wg & 15;
    const int mt   = tile >> 3;        // 0..1  (M tiles of 256)
    const int nt   = tile & 7;         // 0..7  (N tiles of 128)

    const int t   = threadIdx.x;
    const int l   = t & 63;
    const int w   = t >> 6;            // 0..7: wave owns rows w*32..w*32+31
    const int l15 = l & 15, g = l >> 4;

    const size_t MROW = (size_t)NKER * INDIM;

    const float* Abase = X   + (size_t)mt * 256 * MROW + (size_t)kidx * INDIM;
    const float* Bbase = Kn  + (size_t)kidx * INDIM * UNITS + nt * 128;
    float*       Cbase = Out + (size_t)mt * 256 * MROW + (size_t)kidx * UNITS + nt * 128;

    // A direct per-lane: row = w*32 + mi*16 + l15, k = step*32 + g*8
    const float* aP = Abase + (size_t)(w * 32 + l15) * MROW + g * 8;
    // B staging per-lane (verified map): col bn, k-octet bkh
    const int bn = t & 127, bkh = t >> 7;
    const float* bP0 = Bbase + (size_t)bkh * 8 * UNITS + bn;           // even steps
    const float* bP1 = bP0 + (size_t)32 * UNITS;                        // odd steps

    f32x4 acc[2][8];
#pragma unroll
    for (int mi = 0; mi < 2; ++mi)
#pragma unroll
        for (int ni = 0; ni < 8; ++ni)
            acc[mi][ni] = f32x4{0.f, 0.f, 0.f, 0.f};

    f32x4 aw[2][2];          // A prefetch (fp32), one K-step ahead
    float s0[8], s1[8];      // B prefetch sets (even/odd steps)

    auto loadA = [&]() {     // issue A for the NEXT K-step
#pragma unroll
        for (int mi = 0; mi < 2; ++mi) {
            const float* p = aP + (size_t)mi * 16 * MROW;
            aw[mi][0] = *(const f32x4*)(p);
            aw[mi][1] = *(const f32x4*)(p + 4);
        }
        aP += 32;
    };
    auto loadB = [&](float* S, const float*& bP) {
#pragma unroll
        for (int j = 0; j < 8; ++j)
            S[j] = bP[(size_t)j * UNITS];    // 64 consecutive lanes = 256B
        bP += (size_t)64 * UNITS;            // next same-parity step
    };
    auto writeB = [&](const float* S, int bb) {
        u16x8 h;                              // counted vmcnt lands here
#pragma unroll
        for (int j = 0; j < 8; ++j) h[j] = f2bf(S[j]);
        *(u16x8*)&lB[bb][swzidx(bn, bkh * 8)] = h;   // transpose: row=n, k-contig
    };

    bf16x8 af[2];
    auto cvtA = [&]() {       // consume aw (waits its loads), free it for reload
#pragma unroll
        for (int mi = 0; mi < 2; ++mi) {
            u16x8 h;
#pragma unroll
            for (int c = 0; c < 4; ++c) {
                h[c]     = f2bf(aw[mi][0][c]);
                h[c + 4] = f2bf(aw[mi][1][c]);
            }
            af[mi] = __builtin_bit_cast(bf16x8, h);
        }
    };

    bf16x8 bfr[8];
    auto readB = [&](int bb) {
#pragma unroll
        for (int ni = 0; ni < 8; ++ni)
            bfr[ni] = *(const bf16x8*)&lB[bb][swzidx(ni * 16 + l15, g * 8)];
    };
    auto domfma = [&]() {
        LGKM0;                // B frags resident
        SCHED0;               // keep MFMA below the wait (rule #18)
        __builtin_amdgcn_s_setprio(1);
#pragma unroll
        for (int mi = 0; mi < 2; ++mi)
#pragma unroll
            for (int ni = 0; ni < 8; ++ni)
                acc[mi][ni] = __builtin_amdgcn_mfma_f32_16x16x32_bf16(
                    af[mi], bfr[ni], acc[mi][ni], 0, 0, 0);
        __builtin_amdgcn_s_setprio(0);
    };

    // --- prologue ---
    loadB(s0, bP0);          // step 0
    loadB(s1, bP1);          // step 1 (stays in flight)
    loadA();                 // step 0
    writeB(s0, 0);           // counted vmcnt: waits s0 only
    LGKM0;
    BAR();

    // --- main loop: 16 pairs of K-steps, static reg sets ---
#pragma unroll 1
    for (int it = 0; it < 16; ++it) {
        // even step 2it (buf 0)
        cvtA();                          // waits A (issued one step ago)
        loadA();                         // A for step 2it+1 (always exists)
        readB(0);
        if (it < 15) loadB(s0, bP0);     // B for step 2it+2
        domfma();
        BAR();                           // all waves done reading lB[0]
        writeB(s1, 1);                   // step 2it+1 data (loaded 1.5 steps ago)
        LGKM0;
        BAR();
        // odd step 2it+1 (buf 1)
        cvtA();
        if (it < 15) loadA();            // A for step 2it+2
        readB(1);
        if (it < 15) loadB(s1, bP1);     // B for step 2it+3
        domfma();
        if (it < 15) {
            BAR();
            writeB(s0, 0);               // step 2it+2 data
            LGKM0;
            BAR();
        }
    }

    // epilogue: softplus + store (C/D: col=lane&15, row=(lane>>4)*4+reg)
#pragma unroll
    for (int mi = 0; mi < 2; ++mi) {
#pragma unroll
        for (int ni = 0; ni < 8; ++ni) {
            const int n = ni * 16 + l15;
#pragma unroll
            for (int r = 0; r < 4; ++r) {
                const int m = w * 32 + mi * 16 + g * 4 + r;
                const float v  = acc[mi][ni][r];
                const float sp = fmaxf(v, 0.0f) + log1pf(__expf(-fabsf(v)));
                Cbase[(size_t)m * MROW + n] = sp;
            }
        }
    }
}

extern "C" void kernel_launch(void* const* d_in, const int* in_sizes, int n_in,
                              void* d_out, int out_size, void* d_ws, size_t ws_size,
                              hipStream_t stream) {
    const float* X  = (const float*)d_in[0];
    const float* Kn = (const float*)d_in[1];
    float* O = (float*)d_out;
    dense_local<<<2048, 512, 0, stream>>>(X, Kn, O);
}

// Round 7
// 473.954 us; speedup vs baseline: 1.1851x; 1.1851x over previous
//
#include <hip/hip_runtime.h>

#define NKER  128
#define INDIM 1024
#define UNITS 1024

typedef __attribute__((ext_vector_type(8)))  short          bf16x8;
typedef __attribute__((ext_vector_type(4)))  float          f32x4;
typedef __attribute__((ext_vector_type(4)))  unsigned short u16x4;
typedef __attribute__((ext_vector_type(8)))  unsigned short u16x8;

// raw barrier discipline: s_barrier does NOT drain vmcnt; loads issued at
// tile t are consumed (counted vmcnt) at tile t+1 -> ~2 phases of cover.
#define LGKM0   asm volatile("s_waitcnt lgkmcnt(0)" ::: "memory")
#define BAR()   __builtin_amdgcn_s_barrier()
#define SCHED0  __builtin_amdgcn_sched_barrier(0)

__device__ __forceinline__ unsigned short f2bf(float f) {
    return __builtin_bit_cast(unsigned short, static_cast<__bf16>(f));
}

// swizzled LDS element index for (row r, k in 0..31) — verified conflict-free
// and numerically correct in rounds 1-6 (SQ_LDS_BANK_CONFLICT == 0)
__device__ __forceinline__ int swzidx(int r, int k) {
    return r * 32 + ((((k >> 3) ^ ((r >> 1) & 3)) << 3) | (k & 7));
}

__global__ void __launch_bounds__(512, 2)
dense_local(const float* __restrict__ X, const float* __restrict__ Kn,
            float* __restrict__ Out)
{
    // [buf][ksub][row*32 swizzled]: A 64KB + B 32KB = 96KB -> 1 wg/CU
    __shared__ __align__(16) unsigned short lA[2][2][256 * 32];
    __shared__ __align__(16) unsigned short lB[2][2][128 * 32];

    // XCD swizzle: 2048 wgs, 256/XCD, k-major inside an XCD chunk (bijective)
    const int bid  = blockIdx.x;
    const int wg   = (bid & 7) * 256 + (bid >> 3);
    const int kidx = wg >> 4;
    const int tile = wg & 15;
    const int mt   = tile >> 3;        // 0..1  (M tiles of 256)
    const int nt   = tile & 7;         // 0..7  (N tiles of 128)

    const int t   = threadIdx.x;
    const int l   = t & 63;
    const int w   = t >> 6;            // 0..7
    const int wm  = w >> 1;            // wave m-quadrant (64 rows)
    const int wn  = w & 1;             // wave n-half (64 cols)
    const int l15 = l & 15, g = l >> 4;

    const size_t MROW = (size_t)NKER * INDIM;

    const float* Abase = X   + (size_t)mt * 256 * MROW + (size_t)kidx * INDIM;
    const float* Bbase = Kn  + (size_t)kidx * INDIM * UNITS + nt * 128;
    float*       Cbase = Out + (size_t)mt * 256 * MROW + (size_t)kidx * UNITS + nt * 128;

    // staging maps (R2-verified)
    const int ar0 = t >> 3;            // A rows 0..63 (+p*64)
    const int ak4 = (t & 7) << 2;      // A k-quad within 32-k subtile
    const int bn  = t & 127;           // B column (lane-consecutive)
    const int bkh = t >> 7;            // B k-octet within 32-k subtile

    const float* aP = Abase + (size_t)ar0 * MROW + ak4;           // +64/tile
    const float* bP = Bbase + (size_t)bkh * 8 * UNITS + bn;       // +64*UNITS/tile

    f32x4 acc[4][4];
#pragma unroll
    for (int mi = 0; mi < 4; ++mi)
#pragma unroll
        for (int ni = 0; ni < 4; ++ni)
            acc[mi][ni] = f32x4{0.f, 0.f, 0.f, 0.f};

    f32x4 SA[4][2];   // A stage set: [p][ksub], 32 VGPR
    float SB[2][8];   // B stage set: [ksub][j], 16 VGPR

    auto issueA = [&]() {              // one K-tile of A (8 x dwordx4)
#pragma unroll
        for (int p = 0; p < 4; ++p)
#pragma unroll
            for (int s = 0; s < 2; ++s)
                SA[p][s] = *(const f32x4*)(aP + (size_t)p * 64 * MROW + s * 32);
        aP += 64;
    };
    auto issueB = [&]() {              // one K-tile of B (16 x dword, coalesced)
#pragma unroll
        for (int s = 0; s < 2; ++s)
#pragma unroll
            for (int j = 0; j < 8; ++j)
                SB[s][j] = bP[(size_t)(s * 32 + j) * UNITS];
        bP += (size_t)64 * UNITS;
    };
    auto cvtWriteA = [&](int nb) {     // counted vmcnt lands at the cvt
#pragma unroll
        for (int p = 0; p < 4; ++p)
#pragma unroll
            for (int s = 0; s < 2; ++s) {
                u16x4 h;
#pragma unroll
                for (int c = 0; c < 4; ++c) h[c] = f2bf(SA[p][s][c]);
                *(u16x4*)&lA[nb][s][swzidx(ar0 + p * 64, ak4)] = h;
            }
    };
    auto cvtWriteB = [&](int nb) {
#pragma unroll
        for (int s = 0; s < 2; ++s) {
            u16x8 h;
#pragma unroll
            for (int j = 0; j < 8; ++j) h[j] = f2bf(SB[s][j]);
            *(u16x8*)&lB[nb][s][swzidx(bn, bkh * 8)] = h;  // transpose: row=n
        }
    };

    // one K-tile = 2 phases (ksub 0/1); per phase: reads+stage | bar | MFMA | bar
    auto body = [&](int tt, bool wr, bool iss) {
        const int c = tt & 1, nb = c ^ 1;
        bf16x8 af0[4], bf0[4], af1[4], bf1[4];
        // ---- phase 0 (ksub 0) ----
#pragma unroll
        for (int mi = 0; mi < 4; ++mi)
            af0[mi] = *(const bf16x8*)&lA[c][0][swzidx(wm * 64 + mi * 16 + l15, g * 8)];
#pragma unroll
        for (int ni = 0; ni < 4; ++ni)
            bf0[ni] = *(const bf16x8*)&lB[c][0][swzidx(wn * 64 + ni * 16 + l15, g * 8)];
        if (wr)  cvtWriteA(nb);        // tile tt+1 A data (loaded at tile tt-1)
        if (iss) issueA();             // tile tt+2 A loads
        BAR();
        LGKM0; SCHED0;
        __builtin_amdgcn_s_setprio(1);
#pragma unroll
        for (int mi = 0; mi < 4; ++mi)
#pragma unroll
            for (int ni = 0; ni < 4; ++ni)
                acc[mi][ni] = __builtin_amdgcn_mfma_f32_16x16x32_bf16(
                    af0[mi], bf0[ni], acc[mi][ni], 0, 0, 0);
        __builtin_amdgcn_s_setprio(0);
        BAR();
        // ---- phase 1 (ksub 1) ----
#pragma unroll
        for (int mi = 0; mi < 4; ++mi)
            af1[mi] = *(const bf16x8*)&lA[c][1][swzidx(wm * 64 + mi * 16 + l15, g * 8)];
#pragma unroll
        for (int ni = 0; ni < 4; ++ni)
            bf1[ni] = *(const bf16x8*)&lB[c][1][swzidx(wn * 64 + ni * 16 + l15, g * 8)];
        if (wr)  cvtWriteB(nb);        // tile tt+1 B data
        if (iss) issueB();             // tile tt+2 B loads
        BAR();
        LGKM0; SCHED0;
        __builtin_amdgcn_s_setprio(1);
#pragma unroll
        for (int mi = 0; mi < 4; ++mi)
#pragma unroll
            for (int ni = 0; ni < 4; ++ni)
                acc[mi][ni] = __builtin_amdgcn_mfma_f32_16x16x32_bf16(
                    af1[mi], bf1[ni], acc[mi][ni], 0, 0, 0);
        __builtin_amdgcn_s_setprio(0);
        BAR();
    };

    // --- prologue: tile0 staged to buf0; tile1 loads left in flight ---
    issueA();            // t0
    issueB();            // t0
    cvtWriteA(0);        // waits A(t0) via counted vmcnt(16)
    issueA();            // t1
    cvtWriteB(0);        // waits B(t0) via counted vmcnt(8)
    issueB();            // t1
    LGKM0;
    BAR();

    // --- 16 K-tiles: 14 full, 2 peeled (no branches inside bodies) ---
#pragma unroll 1
    for (int tt = 0; tt < 14; ++tt)
        body(tt, true, true);
    body(14, true, false);   // writes tile 15, no more issues
    body(15, false, false);  // compute only

    // epilogue: softplus + store (C/D: col=lane&15, row=(lane>>4)*4+reg)
#pragma unroll
    for (int mi = 0; mi < 4; ++mi) {
#pragma unroll
        for (int ni = 0; ni < 4; ++ni) {
            const int n = wn * 64 + ni * 16 + l15;
#pragma unroll
            for (int r = 0; r < 4; ++r) {
                const int m = wm * 64 + mi * 16 + g * 4 + r;
                const float v  = acc[mi][ni][r];
                const float sp = fmaxf(v, 0.0f) + log1pf(__expf(-fabsf(v)));
                Cbase[(size_t)m * MROW + n] = sp;
            }
        }
    }
}

extern "C" void kernel_launch(void* const* d_in, const int* in_sizes, int n_in,
                              void* d_out, int out_size, void* d_ws, size_t ws_size,
                              hipStream_t stream) {
    const float* X  = (const float*)d_in[0];
    const float* Kn = (const float*)d_in[1];
    float* O = (float*)d_out;
    dense_local<<<2048, 512, 0, stream>>>(X, Kn, O);
}